// Round 9
// baseline (241.083 us; speedup 1.0000x reference)
//
#include <hip/hip_runtime.h>

// DEQ MLP, B=1024, D_IN=512, D_H=1024, D_OUT=512. ALL I/O fp32.
// R20: PERSISTENT KERNEL. R19's REPEAT diagnostic proved warm re-execution
// is ~2-6us vs ~13us cold: per-GEMM cost is the KERNEL BOUNDARY (L2
// invalidate + refetch + ramp), not the loop. Fix: one kernel, 256 blocks
// x 512 thr (1/CU, co-resident: LDS 104KB forces 1/CU and grid == #CU),
// 13 internal barriers. Cross-XCD activation visibility WITHOUT L2
// writeback (R12 lesson): activation stores are write-through to MALL
// (global_store_dwordx4 sc0 sc1); next-phase A-loads are device-coherent
// (global_load_lds aux=17 = sc0|sc1, read at MALL). Weights: normal cached
// loads, L2-resident across ALL phases (nothing invalidates L2). Barrier:
// monotonic counter, vmcnt(0) release + atomicAdd + agent-scope spin.
// MFMA order identical to R19 -> bitwise-same output (absmax 2.441406e-4).

typedef _Float16 f16x8 __attribute__((ext_vector_type(8)));
typedef _Float16 f16x4v __attribute__((ext_vector_type(4)));
typedef float    f32x4 __attribute__((ext_vector_type(4)));
typedef int      i32x4 __attribute__((ext_vector_type(4)));

// weights: normal cached load (L2-resident across phases)
#define GLD_W(gp, lp) __builtin_amdgcn_global_load_lds(                        \
    (const __attribute__((address_space(1))) void*)(gp),                       \
    (__attribute__((address_space(3))) void*)(lp), 16, 0, 0)
// activations: CPol sc0|sc1 = 1|16 = 17 -> device-coherent read at MALL
#define GLD_A(gp, lp) __builtin_amdgcn_global_load_lds(                        \
    (const __attribute__((address_space(1))) void*)(gp),                       \
    (__attribute__((address_space(3))) void*)(lp), 16, 0, 17)

// device-coherent write-through store (reaches MALL; no dirty L2 line)
__device__ __forceinline__ void st_coherent16(void* addr, i32x4 v) {
  asm volatile("global_store_dwordx4 %0, %1, off sc0 sc1"
               :: "v"(addr), "v"(v) : "memory");
}

// Global phase barrier: release = vmcnt(0) (stores are write-through, so
// completion == MALL visibility); arrive via device-scope atomicAdd;
// tid0 spins on agent-scope atomic load; block barrier redistributes.
__device__ __forceinline__ void gbar(unsigned* cnt, unsigned target, int tid) {
  asm volatile("s_waitcnt vmcnt(0)" ::: "memory");
  __builtin_amdgcn_s_barrier();                 // all waves' stores drained
  if (tid == 0) {
    atomicAdd(cnt, 1u);
    while (__hip_atomic_load(cnt, __ATOMIC_RELAXED, __HIP_MEMORY_SCOPE_AGENT)
           < target)
      __builtin_amdgcn_s_sleep(4);
  }
  __builtin_amdgcn_s_barrier();
  asm volatile("" ::: "memory");
}

// One 64x64-tile GEMM phase: out = act(A[.,K] * Bt[N,K]^T + bias).
// BK=128, 8 waves each 16x32, 3 LDS buffers, 2-chunk-deep gld_lds pipeline,
// counted vmcnt(4), one block barrier per K-iter (R19 skeleton, verified).
template<int NITER, bool RELU, bool OUTF32>
__device__ __forceinline__ void gemm_phase(
    const _Float16* __restrict__ A,
    const _Float16* __restrict__ Bt,
    const float* __restrict__ bias,
    _Float16* __restrict__ o16, float* __restrict__ o32,
    _Float16 (*As)[64 * 128], _Float16 (*Bs)[64 * 128], _Float16* Ct,
    int bm, int bn, int N, int K, int w, int quad, int l15, int tid)
{
  const int lr = quad;              // row within 4-row store segment
  const int lc = l15;               // chunk within 256B row
  const _Float16* gA[2];
  const _Float16* gB[2];
  #pragma unroll
  for (int j = 0; j < 2; j++) {
    const int row = 8 * w + 4 * j + lr;
    gA[j] = A  + (size_t)(bm + row) * K + 8 * (lc ^ (row & 15));
    gB[j] = Bt + (size_t)(bn + row) * K + 8 * (lc ^ (row & 15));
  }

  f32x4 acc[2];
  #pragma unroll
  for (int j = 0; j < 2; j++) { f32x4 z{0.f, 0.f, 0.f, 0.f}; acc[j] = z; }

  #define ISSUE(b, c) do {                                                     \
    _Pragma("unroll")                                                          \
    for (int j = 0; j < 2; j++)                                                \
      GLD_A(gA[j] + (size_t)(c) * 128, &As[(b)][(8 * w + 4 * j) * 128]);       \
    _Pragma("unroll")                                                          \
    for (int j = 0; j < 2; j++)                                                \
      GLD_W(gB[j] + (size_t)(c) * 128, &Bs[(b)][(8 * w + 4 * j) * 128]);       \
  } while (0)

  #define COMPUTE(b) do {                                                      \
    f16x8 af[4], bf[2][4];                                                     \
    const int wr_ = (w >> 1) * 16;                                             \
    const int wc_ = (w & 1) * 32;                                              \
    _Pragma("unroll")                                                          \
    for (int k = 0; k < 4; ++k) {                                              \
      const int c_ = ((4 * k + quad) ^ l15) * 8;                               \
      af[k]    = *(const f16x8*)&As[(b)][(wr_      + l15) * 128 + c_];         \
      bf[0][k] = *(const f16x8*)&Bs[(b)][(wc_      + l15) * 128 + c_];         \
      bf[1][k] = *(const f16x8*)&Bs[(b)][(wc_ + 16 + l15) * 128 + c_];         \
    }                                                                          \
    _Pragma("unroll")                                                          \
    for (int k = 0; k < 4; ++k) {                                              \
      acc[0] = __builtin_amdgcn_mfma_f32_16x16x32_f16(af[k], bf[0][k], acc[0], 0, 0, 0); \
      acc[1] = __builtin_amdgcn_mfma_f32_16x16x32_f16(af[k], bf[1][k], acc[1], 0, 0, 0); \
    }                                                                          \
  } while (0)

  ISSUE(0, 0);
  ISSUE(1, 1);
  for (int it = 0; it < NITER - 2; ++it) {
    asm volatile("s_waitcnt vmcnt(4)" ::: "memory");
    __builtin_amdgcn_s_barrier();
    asm volatile("" ::: "memory");
    ISSUE((it + 2) % 3, it + 2);
    COMPUTE(it % 3);
  }
  asm volatile("s_waitcnt vmcnt(4)" ::: "memory");
  __builtin_amdgcn_s_barrier();
  asm volatile("" ::: "memory");
  COMPUTE((NITER - 2) % 3);
  asm volatile("s_waitcnt vmcnt(0)" ::: "memory");
  __builtin_amdgcn_s_barrier();
  asm volatile("" ::: "memory");
  COMPUTE((NITER - 1) % 3);

  #undef ISSUE
  #undef COMPUTE

  // Epilogue. C/D layout (m89-verified): col = lane&15, row = quad*4 + reg.
  const int wr = (w >> 1) * 16;
  const int wc = (w & 1) * 32;
  if (OUTF32) {
    #pragma unroll
    for (int j = 0; j < 2; j++) {
      const int col = bn + wc + j * 16 + l15;
      const float bb = bias[col];
      #pragma unroll
      for (int r = 0; r < 4; r++) {
        const int row = bm + wr + quad * 4 + r;
        float v = acc[j][r] + bb;
        if (RELU) v = fmaxf(v, 0.f);
        o32[(size_t)row * N + col] = v;
      }
    }
  } else {
    // stage fp16 tile in LDS, then coalesced device-coherent 16B stores
    #pragma unroll
    for (int j = 0; j < 2; j++) {
      const int col = wc + j * 16 + l15;
      const float bb = bias[bn + col];
      #pragma unroll
      for (int r = 0; r < 4; r++) {
        const int row = wr + quad * 4 + r;
        float v = acc[j][r] + bb;
        if (RELU) v = fmaxf(v, 0.f);
        Ct[row * 64 + col] = (_Float16)v;
      }
    }
    __syncthreads();
    const int row = tid >> 3, ch = tid & 7;        // 64 rows x 8 chunks x 16B
    i32x4 val = *(const i32x4*)&Ct[row * 64 + ch * 8];
    st_coherent16(o16 + (size_t)(bm + row) * N + bn + ch * 8, val);
  }
}

__global__ __launch_bounds__(512, 1)
void deq_persist(const _Float16* __restrict__ xh,
                 const _Float16* __restrict__ WinT,
                 const _Float16* __restrict__ W1T,
                 const _Float16* __restrict__ W2T,
                 const _Float16* __restrict__ WoutT,
                 const float* __restrict__ b_in,
                 const float* __restrict__ b1,
                 const float* __restrict__ b2,
                 const float* __restrict__ b_out,
                 _Float16* __restrict__ za,
                 _Float16* __restrict__ zb,
                 _Float16* __restrict__ h,
                 float* __restrict__ out,
                 unsigned* __restrict__ cnt)
{
  __shared__ alignas(16) _Float16 As[3][64 * 128];   // 48 KB
  __shared__ alignas(16) _Float16 Bs[3][64 * 128];   // 48 KB
  __shared__ alignas(16) _Float16 Ct[64 * 64];       //  8 KB  (104 KB -> 1 blk/CU)
  const int tid  = threadIdx.x;
  const int w    = tid >> 6;
  const int lane = tid & 63;
  const int quad = lane >> 4;
  const int l15  = lane & 15;
  const int b    = blockIdx.x;
  const int bm   = (b & 15) * 64;
  const int bn   = (b >> 4) * 64;
  unsigned tgt = 0;

  // phase 0: z0 = x @ W_in + b_in   (K=512 -> NITER=4)
  gemm_phase<4, false, false>(xh, WinT, b_in, za, nullptr,
                              As, Bs, Ct, bm, bn, 1024, 512, w, quad, l15, tid);
  tgt += 256; gbar(cnt, tgt, tid);

  // phases 1..12: Picard z <- relu(z@W1+b1)@W2+b2, 6 iterations
  const _Float16* zc = za;
  _Float16* zn = zb;
  #pragma unroll 1
  for (int it = 0; it < 6; ++it) {
    gemm_phase<8, true, false>(zc, W1T, b1, h, nullptr,
                               As, Bs, Ct, bm, bn, 1024, 1024, w, quad, l15, tid);
    tgt += 256; gbar(cnt, tgt, tid);
    gemm_phase<8, false, false>(h, W2T, b2, zn, nullptr,
                                As, Bs, Ct, bm, bn, 1024, 1024, w, quad, l15, tid);
    tgt += 256; gbar(cnt, tgt, tid);
    const _Float16* t = zc; zc = zn; zn = (_Float16*)t;
  }

  // phase 13: out = z* @ W_out + b_out (fp32). 128 tiles; rest exit.
  if (b < 128)
    gemm_phase<8, false, true>(zc, WoutT, b_out, nullptr, out,
                               As, Bs, Ct, bm, bn, 512, 1024, w, quad, l15, tid);
}

// One dispatch: x fp32->fp16 cvt (blocks 0..511, block 0 also zeroes the
// barrier counter), then 32x32 transpose+cvt tiles for the 4 weights.
__global__ __launch_bounds__(256)
void prep_all(const float* __restrict__ x,     _Float16* __restrict__ xh,
              const float* __restrict__ W_in,  _Float16* __restrict__ WinT,
              const float* __restrict__ W1,    _Float16* __restrict__ W1T,
              const float* __restrict__ W2,    _Float16* __restrict__ W2T,
              const float* __restrict__ W_out, _Float16* __restrict__ WoutT,
              unsigned* __restrict__ cnt)
{
  int b = blockIdx.x;
  if (b < 512) {
    if (b == 0 && threadIdx.x == 0) *cnt = 0;           // reset phase counter
    const int i = (b * 256 + threadIdx.x) * 4;          // 512*256*4 = 1024*512
    const float4 v = *(const float4*)(x + i);
    f16x4v hv{(_Float16)v.x, (_Float16)v.y, (_Float16)v.z, (_Float16)v.w};
    *(f16x4v*)(xh + i) = hv;
    return;
  }
  b -= 512;
  const float* src; _Float16* dst; int R, C, bx, by;
  if (b < 512)       { src = W_in;  dst = WinT;  R = 512;  C = 1024; bx = b & 31; by = b >> 5; }
  else if (b < 1536) { b -= 512;  src = W1;    dst = W1T;   R = 1024; C = 1024; bx = b & 31; by = b >> 5; }
  else if (b < 2560) { b -= 1536; src = W2;    dst = W2T;   R = 1024; C = 1024; bx = b & 31; by = b >> 5; }
  else               { b -= 2560; src = W_out; dst = WoutT; R = 1024; C = 512;  bx = b & 15; by = b >> 4; }

  __shared__ float t[32][33];
  const int tx = threadIdx.x & 31;
  const int ty = threadIdx.x >> 5;
  const int c0 = bx * 32;
  const int r0 = by * 32;
  #pragma unroll
  for (int i = 0; i < 32; i += 8)
    t[ty + i][tx] = src[(size_t)(r0 + ty + i) * C + c0 + tx];
  __syncthreads();
  #pragma unroll
  for (int i = 0; i < 32; i += 8)
    dst[(size_t)(c0 + ty + i) * R + r0 + tx] = (_Float16)t[tx][ty + i];
}

extern "C" void kernel_launch(void* const* d_in, const int* in_sizes, int n_in,
                              void* d_out, int out_size, void* d_ws, size_t ws_size,
                              hipStream_t stream) {
  (void)in_sizes; (void)n_in; (void)out_size; (void)ws_size;
  const float* x     = (const float*)d_in[0];
  const float* W_in  = (const float*)d_in[1];
  const float* b_in  = (const float*)d_in[2];
  const float* W1    = (const float*)d_in[3];
  const float* b1    = (const float*)d_in[4];
  const float* W2    = (const float*)d_in[5];
  const float* b2    = (const float*)d_in[6];
  const float* W_out = (const float*)d_in[7];
  const float* b_out = (const float*)d_in[8];
  float* out = (float*)d_out;

  char* p = (char*)d_ws;
  _Float16* xh    = (_Float16*)p; p += (size_t)1024 * 512 * 2;
  _Float16* WinT  = (_Float16*)p; p += (size_t)1024 * 512 * 2;
  _Float16* W1T   = (_Float16*)p; p += (size_t)1024 * 1024 * 2;
  _Float16* W2T   = (_Float16*)p; p += (size_t)1024 * 1024 * 2;
  _Float16* WoutT = (_Float16*)p; p += (size_t)512 * 1024 * 2;
  _Float16* za    = (_Float16*)p; p += (size_t)1024 * 1024 * 2;
  _Float16* zb    = (_Float16*)p; p += (size_t)1024 * 1024 * 2;
  _Float16* h     = (_Float16*)p; p += (size_t)1024 * 1024 * 2;
  unsigned* cnt   = (unsigned*)p;

  prep_all<<<dim3(3584), dim3(256), 0, stream>>>(x, xh, W_in, WinT, W1, W1T,
                                                 W2, W2T, W_out, WoutT, cnt);

  deq_persist<<<dim3(256), dim3(512), 0, stream>>>(
      xh, WinT, W1T, W2T, WoutT, b_in, b1, b2, b_out, za, zb, h, out, cnt);
}

// Round 10
// 233.636 us; speedup vs baseline: 1.0319x; 1.0319x over previous
//
#include <hip/hip_runtime.h>

// DEQ MLP, B=1024, D_IN=512, D_H=1024, D_OUT=512. ALL I/O fp32.
// R21: R20 persistent skeleton, ACTIVATION MEMORY PATH FIXED. R20 forced
// every A-load through MALL (sc0|sc1, ~900cy); phases ran 13us while R19's
// warm-rep diagnostic showed ~6us with L2-served A. Fix: (1) 13 ROTATING
// activation buffers (fresh addresses each phase -> no stale line can exist
// in any L1/L2 -> plain cached loads are correct regardless of XCD mapping);
// (2) A gld_lds back to aux=0 (L2-served; producer/consumer share an XCD
// under round-robin b%8 since stripe m's tiles are all b=m mod 16);
// (3) activation stores stay write-through sc0 sc1 (local L2 keeps the line
// AND MALL is current for the cross-XCD fallback). MFMA order unchanged ->
// bitwise-same output (absmax 2.441406e-4).

typedef _Float16 f16x8 __attribute__((ext_vector_type(8)));
typedef _Float16 f16x4v __attribute__((ext_vector_type(4)));
typedef float    f32x4 __attribute__((ext_vector_type(4)));
typedef int      i32x4 __attribute__((ext_vector_type(4)));

#define GLD16(gp, lp) __builtin_amdgcn_global_load_lds(                        \
    (const __attribute__((address_space(1))) void*)(gp),                       \
    (__attribute__((address_space(3))) void*)(lp), 16, 0, 0)

// device-coherent write-through store (L2 write-through + MALL current)
__device__ __forceinline__ void st_coherent16(void* addr, i32x4 v) {
  asm volatile("global_store_dwordx4 %0, %1, off sc0 sc1"
               :: "v"(addr), "v"(v) : "memory");
}

// Global phase barrier: vmcnt(0) release (write-through stores visible),
// device-scope atomicAdd arrive, tid0 agent-scope spin, block barrier.
__device__ __forceinline__ void gbar(unsigned* cnt, unsigned target, int tid) {
  asm volatile("s_waitcnt vmcnt(0)" ::: "memory");
  __builtin_amdgcn_s_barrier();
  if (tid == 0) {
    atomicAdd(cnt, 1u);
    while (__hip_atomic_load(cnt, __ATOMIC_RELAXED, __HIP_MEMORY_SCOPE_AGENT)
           < target)
      __builtin_amdgcn_s_sleep(4);
  }
  __builtin_amdgcn_s_barrier();
  asm volatile("" ::: "memory");
}

// One 64x64-tile GEMM phase: out = act(A[.,K] * Bt[N,K]^T + bias).
// BK=128, 8 waves each 16x32, 3 LDS buffers, 2-chunk-deep gld_lds pipeline,
// counted vmcnt(4), one block barrier per K-iter (R19/R20 verified skeleton).
template<int NITER, bool RELU, bool OUTF32>
__device__ __forceinline__ void gemm_phase(
    const _Float16* __restrict__ A,
    const _Float16* __restrict__ Bt,
    const float* __restrict__ bias,
    _Float16* __restrict__ o16, float* __restrict__ o32,
    _Float16 (*As)[64 * 128], _Float16 (*Bs)[64 * 128], _Float16* Ct,
    int bm, int bn, int N, int K, int w, int quad, int l15, int tid)
{
  const int lr = quad;              // row within 4-row store segment
  const int lc = l15;               // chunk within 256B row
  const _Float16* gA[2];
  const _Float16* gB[2];
  #pragma unroll
  for (int j = 0; j < 2; j++) {
    const int row = 8 * w + 4 * j + lr;
    gA[j] = A  + (size_t)(bm + row) * K + 8 * (lc ^ (row & 15));
    gB[j] = Bt + (size_t)(bn + row) * K + 8 * (lc ^ (row & 15));
  }

  f32x4 acc[2];
  #pragma unroll
  for (int j = 0; j < 2; j++) { f32x4 z{0.f, 0.f, 0.f, 0.f}; acc[j] = z; }

  #define ISSUE(b, c) do {                                                     \
    _Pragma("unroll")                                                          \
    for (int j = 0; j < 2; j++)                                                \
      GLD16(gA[j] + (size_t)(c) * 128, &As[(b)][(8 * w + 4 * j) * 128]);       \
    _Pragma("unroll")                                                          \
    for (int j = 0; j < 2; j++)                                                \
      GLD16(gB[j] + (size_t)(c) * 128, &Bs[(b)][(8 * w + 4 * j) * 128]);       \
  } while (0)

  #define COMPUTE(b) do {                                                      \
    f16x8 af[4], bf[2][4];                                                     \
    const int wr_ = (w >> 1) * 16;                                             \
    const int wc_ = (w & 1) * 32;                                              \
    _Pragma("unroll")                                                          \
    for (int k = 0; k < 4; ++k) {                                              \
      const int c_ = ((4 * k + quad) ^ l15) * 8;                               \
      af[k]    = *(const f16x8*)&As[(b)][(wr_      + l15) * 128 + c_];         \
      bf[0][k] = *(const f16x8*)&Bs[(b)][(wc_      + l15) * 128 + c_];         \
      bf[1][k] = *(const f16x8*)&Bs[(b)][(wc_ + 16 + l15) * 128 + c_];         \
    }                                                                          \
    _Pragma("unroll")                                                          \
    for (int k = 0; k < 4; ++k) {                                              \
      acc[0] = __builtin_amdgcn_mfma_f32_16x16x32_f16(af[k], bf[0][k], acc[0], 0, 0, 0); \
      acc[1] = __builtin_amdgcn_mfma_f32_16x16x32_f16(af[k], bf[1][k], acc[1], 0, 0, 0); \
    }                                                                          \
  } while (0)

  ISSUE(0, 0);
  ISSUE(1, 1);
  for (int it = 0; it < NITER - 2; ++it) {
    asm volatile("s_waitcnt vmcnt(4)" ::: "memory");
    __builtin_amdgcn_s_barrier();
    asm volatile("" ::: "memory");
    ISSUE((it + 2) % 3, it + 2);
    COMPUTE(it % 3);
  }
  asm volatile("s_waitcnt vmcnt(4)" ::: "memory");
  __builtin_amdgcn_s_barrier();
  asm volatile("" ::: "memory");
  COMPUTE((NITER - 2) % 3);
  asm volatile("s_waitcnt vmcnt(0)" ::: "memory");
  __builtin_amdgcn_s_barrier();
  asm volatile("" ::: "memory");
  COMPUTE((NITER - 1) % 3);

  #undef ISSUE
  #undef COMPUTE

  // Epilogue. C/D layout (m89-verified): col = lane&15, row = quad*4 + reg.
  const int wr = (w >> 1) * 16;
  const int wc = (w & 1) * 32;
  if (OUTF32) {
    #pragma unroll
    for (int j = 0; j < 2; j++) {
      const int col = bn + wc + j * 16 + l15;
      const float bb = bias[col];
      #pragma unroll
      for (int r = 0; r < 4; r++) {
        const int row = bm + wr + quad * 4 + r;
        float v = acc[j][r] + bb;
        if (RELU) v = fmaxf(v, 0.f);
        o32[(size_t)row * N + col] = v;
      }
    }
  } else {
    // stage fp16 tile in LDS, then coalesced write-through 16B stores
    #pragma unroll
    for (int j = 0; j < 2; j++) {
      const int col = wc + j * 16 + l15;
      const float bb = bias[bn + col];
      #pragma unroll
      for (int r = 0; r < 4; r++) {
        const int row = wr + quad * 4 + r;
        float v = acc[j][r] + bb;
        if (RELU) v = fmaxf(v, 0.f);
        Ct[row * 64 + col] = (_Float16)v;
      }
    }
    __syncthreads();
    const int row = tid >> 3, ch = tid & 7;        // 64 rows x 8 chunks x 16B
    i32x4 val = *(const i32x4*)&Ct[row * 64 + ch * 8];
    st_coherent16(o16 + (size_t)(bm + row) * N + bn + ch * 8, val);
  }
}

__global__ __launch_bounds__(512, 1)
void deq_persist(const _Float16* __restrict__ xh,
                 const _Float16* __restrict__ WinT,
                 const _Float16* __restrict__ W1T,
                 const _Float16* __restrict__ W2T,
                 const _Float16* __restrict__ WoutT,
                 const float* __restrict__ b_in,
                 const float* __restrict__ b1,
                 const float* __restrict__ b2,
                 const float* __restrict__ b_out,
                 _Float16* __restrict__ act,      // 13 rotating 2MB buffers
                 float* __restrict__ out,
                 unsigned* __restrict__ cnt)
{
  __shared__ alignas(16) _Float16 As[3][64 * 128];   // 48 KB
  __shared__ alignas(16) _Float16 Bs[3][64 * 128];   // 48 KB
  __shared__ alignas(16) _Float16 Ct[64 * 64];       //  8 KB (104 KB -> 1/CU)
  const int tid  = threadIdx.x;
  const int w    = tid >> 6;
  const int lane = tid & 63;
  const int quad = lane >> 4;
  const int l15  = lane & 15;
  const int b    = blockIdx.x;
  const int bm   = (b & 15) * 64;    // stripe m -> all tiles on XCD m%8
  const int bn   = (b >> 4) * 64;
  const size_t AB = (size_t)1024 * 1024;             // elems per act buffer
  unsigned tgt = 0;

  // phase 0: act0 = x @ W_in + b_in   (K=512 -> NITER=4)
  gemm_phase<4, false, false>(xh, WinT, b_in, act, nullptr,
                              As, Bs, Ct, bm, bn, 1024, 512, w, quad, l15, tid);
  tgt += 256; gbar(cnt, tgt, tid);

  // phases 1..12: Picard, each phase writes a FRESH buffer
  #pragma unroll 1
  for (int it = 0; it < 6; ++it) {
    const _Float16* src = act + (size_t)(2 * it) * AB;
    _Float16* d1 = act + (size_t)(2 * it + 1) * AB;
    _Float16* d2 = act + (size_t)(2 * it + 2) * AB;
    gemm_phase<8, true, false>(src, W1T, b1, d1, nullptr,
                               As, Bs, Ct, bm, bn, 1024, 1024, w, quad, l15, tid);
    tgt += 256; gbar(cnt, tgt, tid);
    gemm_phase<8, false, false>(d1, W2T, b2, d2, nullptr,
                                As, Bs, Ct, bm, bn, 1024, 1024, w, quad, l15, tid);
    tgt += 256; gbar(cnt, tgt, tid);
  }

  // phase 13: out = act12 @ W_out + b_out (fp32). 128 tiles; rest exit.
  if (b < 128)
    gemm_phase<8, false, true>(act + (size_t)12 * AB, WoutT, b_out,
                               nullptr, out,
                               As, Bs, Ct, bm, bn, 512, 1024, w, quad, l15, tid);
}

// One dispatch: x fp32->fp16 cvt (blocks 0..511, block 0 zeroes the barrier
// counter), then 32x32 transpose+cvt tiles for the 4 weights.
__global__ __launch_bounds__(256)
void prep_all(const float* __restrict__ x,     _Float16* __restrict__ xh,
              const float* __restrict__ W_in,  _Float16* __restrict__ WinT,
              const float* __restrict__ W1,    _Float16* __restrict__ W1T,
              const float* __restrict__ W2,    _Float16* __restrict__ W2T,
              const float* __restrict__ W_out, _Float16* __restrict__ WoutT,
              unsigned* __restrict__ cnt)
{
  int b = blockIdx.x;
  if (b < 512) {
    if (b == 0 && threadIdx.x == 0) *cnt = 0;           // reset phase counter
    const int i = (b * 256 + threadIdx.x) * 4;          // 512*256*4 = 1024*512
    const float4 v = *(const float4*)(x + i);
    f16x4v hv{(_Float16)v.x, (_Float16)v.y, (_Float16)v.z, (_Float16)v.w};
    *(f16x4v*)(xh + i) = hv;
    return;
  }
  b -= 512;
  const float* src; _Float16* dst; int R, C, bx, by;
  if (b < 512)       { src = W_in;  dst = WinT;  R = 512;  C = 1024; bx = b & 31; by = b >> 5; }
  else if (b < 1536) { b -= 512;  src = W1;    dst = W1T;   R = 1024; C = 1024; bx = b & 31; by = b >> 5; }
  else if (b < 2560) { b -= 1536; src = W2;    dst = W2T;   R = 1024; C = 1024; bx = b & 31; by = b >> 5; }
  else               { b -= 2560; src = W_out; dst = WoutT; R = 1024; C = 512;  bx = b & 15; by = b >> 4; }

  __shared__ float t[32][33];
  const int tx = threadIdx.x & 31;
  const int ty = threadIdx.x >> 5;
  const int c0 = bx * 32;
  const int r0 = by * 32;
  #pragma unroll
  for (int i = 0; i < 32; i += 8)
    t[ty + i][tx] = src[(size_t)(r0 + ty + i) * C + c0 + tx];
  __syncthreads();
  #pragma unroll
  for (int i = 0; i < 32; i += 8)
    dst[(size_t)(c0 + ty + i) * R + r0 + tx] = (_Float16)t[tx][ty + i];
}

extern "C" void kernel_launch(void* const* d_in, const int* in_sizes, int n_in,
                              void* d_out, int out_size, void* d_ws, size_t ws_size,
                              hipStream_t stream) {
  (void)in_sizes; (void)n_in; (void)out_size; (void)ws_size;
  const float* x     = (const float*)d_in[0];
  const float* W_in  = (const float*)d_in[1];
  const float* b_in  = (const float*)d_in[2];
  const float* W1    = (const float*)d_in[3];
  const float* b1    = (const float*)d_in[4];
  const float* W2    = (const float*)d_in[5];
  const float* b2    = (const float*)d_in[6];
  const float* W_out = (const float*)d_in[7];
  const float* b_out = (const float*)d_in[8];
  float* out = (float*)d_out;

  char* p = (char*)d_ws;
  _Float16* xh    = (_Float16*)p; p += (size_t)1024 * 512 * 2;
  _Float16* WinT  = (_Float16*)p; p += (size_t)1024 * 512 * 2;
  _Float16* W1T   = (_Float16*)p; p += (size_t)1024 * 1024 * 2;
  _Float16* W2T   = (_Float16*)p; p += (size_t)1024 * 1024 * 2;
  _Float16* WoutT = (_Float16*)p; p += (size_t)512 * 1024 * 2;
  _Float16* act   = (_Float16*)p; p += (size_t)13 * 1024 * 1024 * 2;  // 26 MB
  unsigned* cnt   = (unsigned*)p;

  prep_all<<<dim3(3584), dim3(256), 0, stream>>>(x, xh, W_in, WinT, W1, W1T,
                                                 W2, W2T, W_out, WoutT, cnt);

  deq_persist<<<dim3(256), dim3(512), 0, stream>>>(
      xh, WinT, W1T, W2T, WoutT, b_in, b1, b2, b_out, act, out, cnt);
}